// Round 8
// baseline (201.530 us; speedup 1.0000x reference)
//
#include <hip/hip_runtime.h>
#include <hip/hip_bf16.h>

// Problem constants (from reference)
#define NN 4096
#define BB 32
#define CIN 16
#define COUT 64
#define EMB 16
#define KLINK 3
#define WWIN 12
#define BCIN (BB * CIN)   // 512
#define KSPLIT 4
#define KCHUNK (NN / KSPLIT)  // 1024
#define NT (KCHUNK / 32)      // 32 K-iterations per z-chunk

typedef unsigned short ushort_t;
typedef __attribute__((ext_vector_type(8))) short bf16x8;
typedef __attribute__((ext_vector_type(4))) float f32x4;
typedef __attribute__((ext_vector_type(4))) unsigned short us4;
typedef __attribute__((ext_vector_type(8))) unsigned short us8;

static __device__ __forceinline__ ushort_t f2bf(float f) {
  union { float f; unsigned u; } v; v.f = f;
  const unsigned r = v.u + 0x7fffu + ((v.u >> 16) & 1u);  // RNE
  return (ushort_t)(r >> 16);
}

__device__ __forceinline__ void gload16(const void* g, void* l) {
  __builtin_amdgcn_global_load_lds(
      (const __attribute__((address_space(1))) void*)g,
      (__attribute__((address_space(3))) void*)l, 16, 0, 0);
}

// ---------------------------------------------------------------------------
// Kernel 0: prep — Ebf[4096][32] (zero-padded bf16 E), Wpct[4096 j'][32]
// combined weight pool, biasn = E @ biasp, r zeroed.
// ---------------------------------------------------------------------------
__global__ __launch_bounds__(256) void prep_kernel(
    const float* __restrict__ E, const float* __restrict__ Wp,
    const float* __restrict__ Wwp, const float* __restrict__ biasp,
    ushort_t* __restrict__ Ebf, ushort_t* __restrict__ Wpct,
    float* __restrict__ biasn, float* __restrict__ r) {
  const int gid = blockIdx.x * 256 + threadIdx.x;
  if (gid < NN) {
    r[gid] = 0.0f;  // zero rowsum accumulator (pgemm runs after prep)
    const float* e = E + (size_t)gid * EMB;
    ushort_t* o = Ebf + (size_t)gid * 32;
    #pragma unroll
    for (int d = 0; d < 16; ++d) o[d] = f2bf(e[d]);
    #pragma unroll
    for (int d = 16; d < 32; ++d) o[d] = 0;
  } else if (gid < 2 * NN) {
    const int j = gid - NN;
    const int oo = j >> 6;
    const int i = j & 63;
    const int q = i >> 4;
    const int ii = i & 15;
    ushort_t* w = Wpct + (size_t)j * 32;
    #pragma unroll
    for (int d = 0; d < 16; ++d) {
      float v;
      if (q == 0)
        v = Wp[((size_t)(d * 3 + 0) * 16 + ii) * 64 + oo] -
            Wp[((size_t)(d * 3 + 2) * 16 + ii) * 64 + oo];
      else if (q == 1)
        v = Wp[((size_t)(d * 3 + 1) * 16 + ii) * 64 + oo];
      else if (q == 2)
        v = 2.0f * Wp[((size_t)(d * 3 + 2) * 16 + ii) * 64 + oo];
      else
        v = Wwp[((size_t)d * 16 + ii) * 64 + oo];
      w[d] = f2bf(v);
    }
    #pragma unroll
    for (int d = 16; d < 32; ++d) w[d] = 0;
  } else {
    const int t = gid - 2 * NN;
    if (t < NN * 16) {
      const int n = t >> 4;
      const int o4 = t & 15;
      const float4* bp4 = reinterpret_cast<const float4*>(biasp);
      float4 acc = make_float4(0.f, 0.f, 0.f, 0.f);
      #pragma unroll
      for (int d = 0; d < 16; ++d) {
        const float e = E[(size_t)n * EMB + d];
        const float4 b = bp4[d * 16 + o4];
        acc.x += e * b.x; acc.y += e * b.y; acc.z += e * b.z; acc.w += e * b.w;
      }
      *reinterpret_cast<float4*>(biasn + (size_t)n * 64 + o4 * 4) = acc;
    }
  }
}

// ---------------------------------------------------------------------------
// Kernel 1: uber — heterogeneous fusion of {pgemm, Wall gemm, transpose_x}.
// 6144 blocks = 512 groups x 12, interleaved 4:4:4.
// ---------------------------------------------------------------------------
__global__ __launch_bounds__(256) void uber_kernel(
    const ushort_t* __restrict__ Ebf, const ushort_t* __restrict__ Wpct,
    ushort_t* __restrict__ Wall, ushort_t* __restrict__ Pb,
    float* __restrict__ r,
    const float* __restrict__ x, ushort_t* __restrict__ XtT) {
  __shared__ ushort_t smem[6144];  // 12 KB: GEMM As(4096)+Bs(2048) / tx tile
  const int bid = blockIdx.x;
  const int tid = threadIdx.x;
  const int g = bid / 12;
  const int rm = bid - g * 12;

  if (rm < 4) {
    // ---- pgemm: Pb = exp(relu(E E^T)-16) bf16 + rowsums (atomics) ----
    const int pidx = g * 4 + rm;          // 0..2047
    const int row0 = (pidx >> 6) * 128;
    const int col0 = (pidx & 63) * 64;
    ushort_t* As = smem;                  // 128x32
    ushort_t* Bs = smem + 4096;           // 64x32
    const int lane = tid & 63;
    const int wid = tid >> 6;
    const int wr = wid >> 1;
    const int wc = wid & 1;
    const int sr = tid >> 2;
    const int scs = (((tid & 3) ^ (sr & 3)) * 8);
    gload16(Ebf + (size_t)(row0 + sr) * 32 + scs, &As[tid * 8]);
    gload16(Ebf + (size_t)(row0 + 64 + sr) * 32 + scs, &As[2048 + tid * 8]);
    gload16(Ebf + (size_t)(col0 + sr) * 32 + scs, &Bs[tid * 8]);
    __syncthreads();

    const int kq = (lane >> 4) * 8;
    const int fr = lane & 15;
    bf16x8 af[4], bfr[2];
    #pragma unroll
    for (int i = 0; i < 4; ++i) {
      const int rr = wr * 64 + i * 16 + fr;
      af[i] = *reinterpret_cast<const bf16x8*>(&As[rr * 32 + (kq ^ ((rr & 3) * 8))]);
    }
    #pragma unroll
    for (int j = 0; j < 2; ++j) {
      const int rr = wc * 32 + j * 16 + fr;
      bfr[j] = *reinterpret_cast<const bf16x8*>(&Bs[rr * 32 + (kq ^ ((rr & 3) * 8))]);
    }
    f32x4 acc[4][2];
    #pragma unroll
    for (int i = 0; i < 4; ++i)
      #pragma unroll
      for (int j = 0; j < 2; ++j) acc[i][j] = (f32x4){0.f, 0.f, 0.f, 0.f};
    #pragma unroll
    for (int i = 0; i < 4; ++i)
      #pragma unroll
      for (int j = 0; j < 2; ++j)
        acc[i][j] = __builtin_amdgcn_mfma_f32_16x16x32_bf16(af[i], bfr[j],
                                                            acc[i][j], 0, 0, 0);
    float pv[4][2][4];
    #pragma unroll
    for (int i = 0; i < 4; ++i) {
      const int rg = row0 + wr * 64 + i * 16 + ((lane >> 4) << 2);
      #pragma unroll
      for (int j = 0; j < 2; ++j) {
        const int cg = col0 + wc * 32 + j * 16 + (lane & 15);
        us4 o;
        #pragma unroll
        for (int q = 0; q < 4; ++q) {
          const float p = __expf(fmaxf(acc[i][j][q], 0.0f) - 16.0f);
          pv[i][j][q] = p;
          o[q] = f2bf(p);
        }
        *reinterpret_cast<us4*>(&Pb[(size_t)cg * NN + rg]) = o;
      }
    }
    #pragma unroll
    for (int i = 0; i < 4; ++i) {
      const int rg = row0 + wr * 64 + i * 16 + ((lane >> 4) << 2);
      #pragma unroll
      for (int q = 0; q < 4; ++q) {
        float s = pv[i][0][q] + pv[i][1][q];
        s += __shfl_xor(s, 1, 64);
        s += __shfl_xor(s, 2, 64);
        s += __shfl_xor(s, 4, 64);
        s += __shfl_xor(s, 8, 64);
        if ((lane & 15) == 0) atomicAdd(&r[rg + q], s);
      }
    }
  } else if (rm < 8) {
    // ---- Wall gemm: Wall[n][j'] = (Wpct @ Ebf^T)^T, K=32 single-step ----
    const int widx = g * 4 + (rm - 4);    // 0..2047
    const int row0 = (widx >> 6) * 128;   // j' rows
    const int col0 = (widx & 63) * 64;    // n cols
    ushort_t* As = smem;
    ushort_t* Bs = smem + 4096;
    const int lane = tid & 63;
    const int wid = tid >> 6;
    const int wr = wid >> 1;
    const int wc = wid & 1;
    const int sr = tid >> 2;
    const int scs = (((tid & 3) ^ (sr & 3)) * 8);
    gload16(Wpct + (size_t)(row0 + sr) * 32 + scs, &As[tid * 8]);
    gload16(Wpct + (size_t)(row0 + 64 + sr) * 32 + scs, &As[2048 + tid * 8]);
    gload16(Ebf + (size_t)(col0 + sr) * 32 + scs, &Bs[tid * 8]);
    __syncthreads();

    const int kq = (lane >> 4) * 8;
    const int fr = lane & 15;
    bf16x8 af[4], bfr[2];
    #pragma unroll
    for (int i = 0; i < 4; ++i) {
      const int rr = wr * 64 + i * 16 + fr;
      af[i] = *reinterpret_cast<const bf16x8*>(&As[rr * 32 + (kq ^ ((rr & 3) * 8))]);
    }
    #pragma unroll
    for (int j = 0; j < 2; ++j) {
      const int rr = wc * 32 + j * 16 + fr;
      bfr[j] = *reinterpret_cast<const bf16x8*>(&Bs[rr * 32 + (kq ^ ((rr & 3) * 8))]);
    }
    f32x4 acc[4][2];
    #pragma unroll
    for (int i = 0; i < 4; ++i)
      #pragma unroll
      for (int j = 0; j < 2; ++j) acc[i][j] = (f32x4){0.f, 0.f, 0.f, 0.f};
    #pragma unroll
    for (int i = 0; i < 4; ++i)
      #pragma unroll
      for (int j = 0; j < 2; ++j)
        acc[i][j] = __builtin_amdgcn_mfma_f32_16x16x32_bf16(af[i], bfr[j],
                                                            acc[i][j], 0, 0, 0);
    #pragma unroll
    for (int i = 0; i < 4; ++i) {
      const int rg = row0 + wr * 64 + i * 16 + ((lane >> 4) << 2);
      #pragma unroll
      for (int j = 0; j < 2; ++j) {
        const int cg = col0 + wc * 32 + j * 16 + (lane & 15);
        us4 o;
        o.x = f2bf(acc[i][j][0]);
        o.y = f2bf(acc[i][j][1]);
        o.z = f2bf(acc[i][j][2]);
        o.w = f2bf(acc[i][j][3]);
        *reinterpret_cast<us4*>(&Wall[(size_t)cg * NN + rg]) = o;
      }
    }
  } else {
    // ---- transpose_x: XtT[b*CIN+c][m] = bf16(x[b][m][c]) ----
    const int txidx = g * 4 + (rm - 8);   // 0..2047
    const int b = txidx >> 6;
    const int m0 = (txidx & 63) * 64;
    ushort_t (*T)[72] = reinterpret_cast<ushort_t(*)[72]>(smem);
    const int i = tid & 15;
    const int ml = tid >> 4;
    #pragma unroll
    for (int it = 0; it < 4; ++it) {
      const int m = m0 + ml + it * 16;
      T[i][ml + it * 16] = f2bf(x[((size_t)b * NN + m) * CIN + i]);
    }
    __syncthreads();
    if (tid < 128) {
      const int rr = tid >> 3;
      const int c8 = (tid & 7) * 8;
      const us8 v = *reinterpret_cast<const us8*>(&T[rr][c8]);
      *reinterpret_cast<us8*>(&XtT[(size_t)(b * CIN + rr) * NN + m0 + c8]) = v;
    }
  }
}

// ---------------------------------------------------------------------------
// Kernel 2b: split-K MFMA GEMM fused with a time_mix half.
// Grid = 1536 blocks: g = bid/3, rm = bid%3. rm<2 -> splitk sub-block
// (sid = g*2+rm, 0..1023, XCD-swizzled); rm==2 -> time_mix block
// (tmIdx = tmBase + g; tmBase 0 covers b<16, tmBase 512 covers b>=16).
// tm blocks interleave 2:1 through the dispatch so each CU co-resides
// MFMA splitk blocks with the HBM-latency-bound xw gather -> overlap
// (R6 evidence: co-resident independent work rides nearly free under tm).
// splitk: depth-2 pipeline, 3 LDS buffers, counted vmcnt(6) across raw
// s_barriers (loads stay in flight). gx,gy passed for tile decode.
// ---------------------------------------------------------------------------
template <int CUR>
__device__ __forceinline__ void compute_tile(
    const ushort_t (&As)[3][128 * 32], const ushort_t (&Bs)[3][64 * 32],
    f32x4 (&acc)[4][2], int wr, int wc, int kq, int fr) {
  bf16x8 af[4], bfr[2];
  #pragma unroll
  for (int i = 0; i < 4; ++i) {
    const int rr = wr * 64 + i * 16 + fr;
    af[i] = *reinterpret_cast<const bf16x8*>(
        &As[CUR][rr * 32 + (kq ^ ((rr & 3) * 8))]);
  }
  #pragma unroll
  for (int j = 0; j < 2; ++j) {
    const int rr = wc * 32 + j * 16 + fr;
    bfr[j] = *reinterpret_cast<const bf16x8*>(
        &Bs[CUR][rr * 32 + (kq ^ ((rr & 3) * 8))]);
  }
  #pragma unroll
  for (int i = 0; i < 4; ++i)
    #pragma unroll
    for (int j = 0; j < 2; ++j)
      acc[i][j] = __builtin_amdgcn_mfma_f32_16x16x32_bf16(af[i], bfr[j],
                                                          acc[i][j], 0, 0, 0);
}

__global__ __launch_bounds__(256) void gemm_splitk_tm_kernel(
    const ushort_t* __restrict__ Ag, const ushort_t* __restrict__ Bt,
    float* __restrict__ Cp, int lda, int ldb, int ldc, int gx, int gy,
    const float* __restrict__ xw, const float* __restrict__ Tv,
    float* __restrict__ XW, int tmBase) {
  __shared__ ushort_t As[3][128 * 32];
  __shared__ ushort_t Bs[3][64 * 32];
  const int tid = threadIdx.x;
  const int g = blockIdx.x / 3;
  const int rm = blockIdx.x - g * 3;

  if (rm == 2) {
    // ---- time_mix half: XW[b][n][i] = sum_t xw[b][t][n][i]*T[t] ----
    const int lin = (tmBase + g) * 256 + tid;
    const int c4 = (lin & 3) << 2;
    const int nn0 = ((lin >> 6) & 127) * 32 + ((lin >> 2) & 15);
    const int b = lin >> 13;
    float tv[WWIN];
    #pragma unroll
    for (int t = 0; t < WWIN; ++t) tv[t] = Tv[t];
    float4 a0 = make_float4(0.f, 0.f, 0.f, 0.f);
    float4 a1 = make_float4(0.f, 0.f, 0.f, 0.f);
    #pragma unroll 3
    for (int t = 0; t < WWIN; ++t) {
      const float4 v0 = *reinterpret_cast<const float4*>(
          xw + (((size_t)b * WWIN + t) * NN + nn0) * CIN + c4);
      const float4 v1 = *reinterpret_cast<const float4*>(
          xw + (((size_t)b * WWIN + t) * NN + nn0 + 16) * CIN + c4);
      a0.x += v0.x * tv[t]; a0.y += v0.y * tv[t];
      a0.z += v0.z * tv[t]; a0.w += v0.w * tv[t];
      a1.x += v1.x * tv[t]; a1.y += v1.y * tv[t];
      a1.z += v1.z * tv[t]; a1.w += v1.w * tv[t];
    }
    *reinterpret_cast<float4*>(XW + ((size_t)b * NN + nn0) * CIN + c4) = a0;
    *reinterpret_cast<float4*>(XW + ((size_t)b * NN + nn0 + 16) * CIN + c4) = a1;
    return;
  }

  const int lane = tid & 63;
  const int wid = tid >> 6;
  const int wr = wid >> 1;
  const int wc = wid & 1;

  // XCD-aware bijective remap over the 1024 splitk sub-blocks.
  const int sid = g * 2 + rm;            // 0..1023
  const int L = (sid & 7) * 128 + (sid >> 3);
  const int bx = L % gx;
  const int by = (L / gx) % gy;
  const int bz = L / (gx * gy);

  const int row0 = by * 128;
  const int col0 = bx * 64;
  const int kbase = bz * KCHUNK;

  f32x4 acc[4][2];
  #pragma unroll
  for (int i = 0; i < 4; ++i)
    #pragma unroll
    for (int j = 0; j < 2; ++j) acc[i][j] = (f32x4){0.f, 0.f, 0.f, 0.f};

  const int sr = tid >> 2;
  const int scs = (((tid & 3) ^ (sr & 3)) * 8);
  const ushort_t* agp0 = Ag + (size_t)(row0 + sr) * lda + scs;
  const ushort_t* agp1 = Ag + (size_t)(row0 + 64 + sr) * lda + scs;
  const ushort_t* bgp  = Bt + (size_t)(col0 + sr) * ldb + scs;

  const int kq = (lane >> 4) * 8;
  const int fr = lane & 15;

#define STAGE(BUF, KB)                              \
  gload16(agp0 + (KB), &As[BUF][tid * 8]);          \
  gload16(agp1 + (KB), &As[BUF][2048 + tid * 8]);   \
  gload16(bgp + (KB), &Bs[BUF][tid * 8]);

#define PIPE_STEP(CUR, NB, TT)                                  \
  STAGE(NB, kbase + ((TT) + 2) * 32);                           \
  asm volatile("s_waitcnt vmcnt(6)" ::: "memory");              \
  __builtin_amdgcn_s_barrier();                                 \
  __builtin_amdgcn_sched_barrier(0);                            \
  compute_tile<CUR>(As, Bs, acc, wr, wc, kq, fr);               \
  __builtin_amdgcn_sched_barrier(0);                            \
  __builtin_amdgcn_s_barrier();

  // prologue: stage tiles 0 and 1 (6 loads in flight per thread)
  STAGE(0, kbase);
  STAGE(1, kbase + 32);

  // main loop: t = 0..NT-3, statically unrolled x3 (NT-2 = 30 = 3*10)
  for (int tt = 0; tt < (NT - 2) / 3; ++tt) {
    const int t3 = tt * 3;
    PIPE_STEP(0, 2, t3 + 0);
    PIPE_STEP(1, 0, t3 + 1);
    PIPE_STEP(2, 1, t3 + 2);
  }
  // tail t = NT-2 (cur = 0): only tile NT-1's 3 loads outstanding
  asm volatile("s_waitcnt vmcnt(3)" ::: "memory");
  __builtin_amdgcn_s_barrier();
  __builtin_amdgcn_sched_barrier(0);
  compute_tile<0>(As, Bs, acc, wr, wc, kq, fr);
  __builtin_amdgcn_sched_barrier(0);
  __builtin_amdgcn_s_barrier();
  // tail t = NT-1 (cur = 1)
  asm volatile("s_waitcnt vmcnt(0)" ::: "memory");
  __builtin_amdgcn_s_barrier();
  __builtin_amdgcn_sched_barrier(0);
  compute_tile<1>(As, Bs, acc, wr, wc, kq, fr);

#undef PIPE_STEP
#undef STAGE

  float* cpz = Cp + (size_t)bz * ((size_t)BCIN * NN);
  #pragma unroll
  for (int i = 0; i < 4; ++i) {
    const int rg = row0 + wr * 64 + i * 16 + ((lane >> 4) << 2);
    #pragma unroll
    for (int j = 0; j < 2; ++j) {
      const int cg = col0 + wc * 32 + j * 16 + (lane & 15);
      *reinterpret_cast<f32x4*>(&cpz[(size_t)cg * ldc + rg]) = acc[i][j];
    }
  }
}

// ---------------------------------------------------------------------------
// Kernel 2c: Y1 reduce + transpose (fused). Sums KSPLIT f32 partials of
// Cpart[bc][n], scales by 1/R[n], writes Y1T[bc][n] (coalesced) AND
// Y1n[n][bc] via LDS 64x64 transpose. grid (NN/64, BCIN/64) = 512 blocks.
// ---------------------------------------------------------------------------
__global__ __launch_bounds__(256) void reduce_y1_kernel(
    const float* __restrict__ Cp, const float* __restrict__ R,
    ushort_t* __restrict__ Y1T, ushort_t* __restrict__ Y1n) {
  __shared__ ushort_t T[64][72];
  const int n0 = blockIdx.x * 64;
  const int bc0 = blockIdx.y * 64;
  const int tid = threadIdx.x;
  const size_t SS = (size_t)BCIN * NN;
  #pragma unroll
  for (int q = 0; q < 4; ++q) {
    const int lin = tid + q * 256;
    const int bc = lin >> 4;          // 0..63
    const int nc = (lin & 15) * 4;    // 0..60
    const size_t base = (size_t)(bc0 + bc) * NN + n0 + nc;
    float4 s = *reinterpret_cast<const float4*>(Cp + base);
    #pragma unroll
    for (int z = 1; z < KSPLIT; ++z) {
      const float4 v = *reinterpret_cast<const float4*>(Cp + (size_t)z * SS + base);
      s.x += v.x; s.y += v.y; s.z += v.z; s.w += v.w;
    }
    const float4 rv = *reinterpret_cast<const float4*>(R + n0 + nc);
    us4 o;
    o.x = f2bf(s.x / rv.x); o.y = f2bf(s.y / rv.y);
    o.z = f2bf(s.z / rv.z); o.w = f2bf(s.w / rv.w);
    *reinterpret_cast<us4*>(&Y1T[base]) = o;
    *reinterpret_cast<us4*>(&T[bc][nc]) = o;
  }
  __syncthreads();
  #pragma unroll
  for (int t = 0; t < 2; ++t) {
    const int lin = tid + t * 256;
    const int nr = lin >> 3;
    const int ch = lin & 7;
    us8 v;
    #pragma unroll
    for (int e = 0; e < 8; ++e) v[e] = T[ch * 8 + e][nr];
    *reinterpret_cast<us8*>(&Y1n[(size_t)(n0 + nr) * BCIN + bc0 + ch * 8]) = v;
  }
}

// ---------------------------------------------------------------------------
// Kernel 2d: Y2 reduce. Sums KSPLIT f32 partials of Cpart[n][bc] layout,
// scales by 1/R[n] (e>>9), writes Y2n bf16. grid 2048 blocks.
// ---------------------------------------------------------------------------
__global__ __launch_bounds__(256) void reduce_y2_kernel(
    const float* __restrict__ Cp, ushort_t* __restrict__ Ct,
    const float* __restrict__ R) {
  const size_t e = ((size_t)blockIdx.x * 256 + threadIdx.x) << 2;
  const size_t SS = (size_t)BCIN * NN;
  float4 s = *reinterpret_cast<const float4*>(Cp + e);
  #pragma unroll
  for (int z = 1; z < KSPLIT; ++z) {
    const float4 v = *reinterpret_cast<const float4*>(Cp + (size_t)z * SS + e);
    s.x += v.x; s.y += v.y; s.z += v.z; s.w += v.w;
  }
  const float ri = 1.0f / R[e >> 9];
  s.x *= ri; s.y *= ri; s.z *= ri; s.w *= ri;
  us4 o;
  o.x = f2bf(s.x); o.y = f2bf(s.y); o.z = f2bf(s.z); o.w = f2bf(s.w);
  *reinterpret_cast<us4*>(Ct + e) = o;
}

// ---------------------------------------------------------------------------
// Kernel 7: combine via per-node MFMA. One wave per node (2 nodes/wave),
// 512 blocks x 4 waves. Per node: out[32b x 64o] = V[32x64] @ W[64x64] + bias
// ---------------------------------------------------------------------------
__global__ __launch_bounds__(256) void combine_kernel(
    const float* __restrict__ x, const ushort_t* __restrict__ Y1n,
    const ushort_t* __restrict__ Y2n, const float* __restrict__ XW,
    const ushort_t* __restrict__ Wall, const float* __restrict__ biasn,
    float* __restrict__ out) {
  __shared__ ushort_t lds[4 * 6144];  // per wave: W 4096 us + V 2048 us
  const int tid = threadIdx.x;
  const int lane = tid & 63;
  const int w = tid >> 6;
  ushort_t* Wl = lds + w * 6144;
  ushort_t* Vl = Wl + 4096;

  const int perm = ((lane >> 3) << 3) | ((lane & 7) ^ (lane >> 3));
  const int vb = lane >> 1;
  const int i0 = (lane & 1) * 8;

  for (int it = 0; it < 2; ++it) {
    const int n = blockIdx.x * 8 + w * 2 + it;
    asm volatile("s_waitcnt lgkmcnt(0)" ::: "memory");

    const ushort_t* wrow = Wall + (size_t)n * 4096;
    #pragma unroll
    for (int q = 0; q < 8; ++q)
      gload16(wrow + q * 512 + perm * 8, Wl + q * 512);

    const float4* xp = reinterpret_cast<const float4*>(
        x + ((size_t)vb * NN + n) * CIN + i0);
    const float4 xa = xp[0], xb = xp[1];
    const us8 y1 = *reinterpret_cast<const us8*>(Y1n + (size_t)n * BCIN + lane * 8);
    const us8 y2 = *reinterpret_cast<const us8*>(Y2n + (size_t)n * BCIN + lane * 8);
    const float4* xwp = reinterpret_cast<const float4*>(
        XW + ((size_t)vb * NN + n) * CIN + i0);
    const float4 wa = xwp[0], wb = xwp[1];
    us8 xv, wv;
    xv[0] = f2bf(xa.x); xv[1] = f2bf(xa.y); xv[2] = f2bf(xa.z); xv[3] = f2bf(xa.w);
    xv[4] = f2bf(xb.x); xv[5] = f2bf(xb.y); xv[6] = f2bf(xb.z); xv[7] = f2bf(xb.w);
    wv[0] = f2bf(wa.x); wv[1] = f2bf(wa.y); wv[2] = f2bf(wa.z); wv[3] = f2bf(wa.w);
    wv[4] = f2bf(wb.x); wv[5] = f2bf(wb.y); wv[6] = f2bf(wb.z); wv[7] = f2bf(wb.w);
    const int c0 = (lane & 1);
    const int vswz = vb & 7;
    *reinterpret_cast<us8*>(Vl + vb * 64 + (((c0 + 0) ^ vswz) << 3)) = xv;
    *reinterpret_cast<us8*>(Vl + vb * 64 + (((c0 + 2) ^ vswz) << 3)) = y1;
    *reinterpret_cast<us8*>(Vl + vb * 64 + (((c0 + 4) ^ vswz) << 3)) = y2;
    *reinterpret_cast<us8*>(Vl + vb * 64 + (((c0 + 6) ^ vswz) << 3)) = wv;

    f32x4 acc[2][4];
    #pragma unroll
    for (int nt = 0; nt < 4; ++nt) {
      const float bv = biasn[(size_t)n * 64 + nt * 16 + (lane & 15)];
      acc[0][nt] = (f32x4){bv, bv, bv, bv};
      acc[1][nt] = (f32x4){bv, bv, bv, bv};
    }

    asm volatile("s_waitcnt vmcnt(0)" ::: "memory");

    bf16x8 af[2][2], bfr[4][2];
    #pragma unroll
    for (int mt = 0; mt < 2; ++mt)
      #pragma unroll
      for (int kt = 0; kt < 2; ++kt) {
        const int rr = mt * 16 + (lane & 15);
        const int c = kt * 4 + (lane >> 4);
        af[mt][kt] = *reinterpret_cast<const bf16x8*>(
            Vl + rr * 64 + ((c ^ (lane & 7)) << 3));
      }
    #pragma unroll
    for (int nt = 0; nt < 4; ++nt)
      #pragma unroll
      for (int kt = 0; kt < 2; ++kt) {
        const int o = nt * 16 + (lane & 15);
        const int c = kt * 4 + (lane >> 4);
        bfr[nt][kt] = *reinterpret_cast<const bf16x8*>(
            Wl + o * 64 + ((c ^ (lane & 7)) << 3));
      }
    #pragma unroll
    for (int mt = 0; mt < 2; ++mt)
      #pragma unroll
      for (int nt = 0; nt < 4; ++nt)
        #pragma unroll
        for (int kt = 0; kt < 2; ++kt)
          acc[mt][nt] = __builtin_amdgcn_mfma_f32_16x16x32_bf16(
              af[mt][kt], bfr[nt][kt], acc[mt][nt], 0, 0, 0);

    #pragma unroll
    for (int mt = 0; mt < 2; ++mt)
      #pragma unroll
      for (int nt = 0; nt < 4; ++nt) {
        const int o = nt * 16 + (lane & 15);
        #pragma unroll
        for (int rr = 0; rr < 4; ++rr) {
          const int b = mt * 16 + ((lane >> 4) << 2) + rr;
          out[((size_t)b * NN + n) * COUT + o] = acc[mt][nt][rr];
        }
      }
  }
}

// ---------------------------------------------------------------------------
extern "C" void kernel_launch(void* const* d_in, const int* in_sizes, int n_in,
                              void* d_out, int out_size, void* d_ws,
                              size_t ws_size, hipStream_t stream) {
  const float* x = (const float*)d_in[0];        // [B,N,CIN]
  const float* x_window = (const float*)d_in[1]; // [B,WIN,N,CIN]
  const float* E = (const float*)d_in[2];        // [N,EMB]
  const float* Wp = (const float*)d_in[3];       // [EMB,K,CIN,COUT]
  const float* Wwp = (const float*)d_in[4];      // [EMB,CIN,COUT]
  const float* biasp = (const float*)d_in[5];    // [EMB,COUT]
  const float* Tv = (const float*)d_in[6];       // [WIN]
  float* out = (float*)d_out;                    // [B,N,COUT] f32

  // Workspace layout
  char* p = (char*)d_ws;
  float* XW = (float*)p;                 p += (size_t)BB * NN * CIN * 4;
  ushort_t* Pb = (ushort_t*)p;           p += (size_t)NN * NN * 2;
  ushort_t* XtT = (ushort_t*)p;          p += (size_t)BCIN * NN * 2;
  ushort_t* Y1T = (ushort_t*)p;          p += (size_t)BCIN * NN * 2;
  ushort_t* Y2n = (ushort_t*)p;          p += (size_t)NN * BCIN * 2;
  ushort_t* Y1n = (ushort_t*)p;          p += (size_t)NN * BCIN * 2;
  ushort_t* Wall = (ushort_t*)p;         p += (size_t)NN * 4096 * 2;
  ushort_t* Ebf = (ushort_t*)p;          p += (size_t)NN * 32 * 2;
  ushort_t* Wpct = (ushort_t*)p;         p += (size_t)NN * 32 * 2;
  float* biasn = (float*)p;              p += (size_t)NN * 64 * 4;
  float* r = (float*)p;                  p += (size_t)NN * 4;
  float* Cpart = (float*)p;              p += (size_t)KSPLIT * BCIN * NN * 4;

  // prep (tiny) -> uber {pgemm + Wall + transpose_x} fused.
  prep_kernel<<<288, 256, 0, stream>>>(E, Wp, Wwp, biasp, Ebf, Wpct, biasn, r);
  uber_kernel<<<6144, 256, 0, stream>>>(Ebf, Wpct, Wall, Pb, r, x, XtT);
  // Y1 partials (layout [bc][n]) fused with time_mix half A (b 0..15):
  // 1536 blocks, 2 splitk : 1 tm interleave. gx=8, gy=32.
  gemm_splitk_tm_kernel<<<1536, 256, 0, stream>>>(
      Pb, XtT, Cpart, NN, NN, NN, BCIN / 64, NN / 128,
      x_window, Tv, XW, 0);
  // Y1 reduce + normalize + dual-layout store (Y1T + Y1n)
  reduce_y1_kernel<<<dim3(NN / 64, BCIN / 64), 256, 0, stream>>>(
      Cpart, r, Y1T, Y1n);
  // Y2 partials (layout [n][bc]) fused with time_mix half B (b 16..31):
  // gx=64, gy=4.
  gemm_splitk_tm_kernel<<<1536, 256, 0, stream>>>(
      Y1T, Pb, Cpart, NN, NN, BCIN, NN / 64, BCIN / 128,
      x_window, Tv, XW, 512);
  reduce_y2_kernel<<<(BCIN * NN / 4) / 256, 256, 0, stream>>>(Cpart, Y2n, r);
  // combine: per-node V[32x64] @ W[64x64] + bias
  combine_kernel<<<NN / 8, 256, 0, stream>>>(x, Y1n, Y2n, XW, Wall, biasn, out);
}

// Round 9
// 174.826 us; speedup vs baseline: 1.1527x; 1.1527x over previous
//
#include <hip/hip_runtime.h>
#include <hip/hip_bf16.h>

// Problem constants (from reference)
#define NN 4096
#define BB 32
#define CIN 16
#define COUT 64
#define EMB 16
#define KLINK 3
#define WWIN 12
#define BCIN (BB * CIN)   // 512
#define KSPLIT 4
#define KCHUNK (NN / KSPLIT)  // 1024
#define NT (KCHUNK / 32)      // 32 K-iterations per z-chunk

typedef unsigned short ushort_t;
typedef __attribute__((ext_vector_type(8))) short bf16x8;
typedef __attribute__((ext_vector_type(4))) float f32x4;
typedef __attribute__((ext_vector_type(4))) unsigned short us4;
typedef __attribute__((ext_vector_type(8))) unsigned short us8;

static __device__ __forceinline__ ushort_t f2bf(float f) {
  union { float f; unsigned u; } v; v.f = f;
  const unsigned r = v.u + 0x7fffu + ((v.u >> 16) & 1u);  // RNE
  return (ushort_t)(r >> 16);
}

__device__ __forceinline__ void gload16(const void* g, void* l) {
  __builtin_amdgcn_global_load_lds(
      (const __attribute__((address_space(1))) void*)g,
      (__attribute__((address_space(3))) void*)l, 16, 0, 0);
}

// Nontemporal float4 load: xw is read exactly once -> evict-first so it
// doesn't thrash Pb/Wall/XtT out of L2/L3 before the splitk GEMMs read them.
__device__ __forceinline__ float4 nt_load4(const float* p) {
  const f32x4 v = __builtin_nontemporal_load(reinterpret_cast<const f32x4*>(p));
  return make_float4(v[0], v[1], v[2], v[3]);
}

// ---------------------------------------------------------------------------
// Kernel 0: prep — Ebf[4096][32] (zero-padded bf16 E), Wpct[4096 j'][32]
// combined weight pool, biasn = E @ biasp, r zeroed.
// ---------------------------------------------------------------------------
__global__ __launch_bounds__(256) void prep_kernel(
    const float* __restrict__ E, const float* __restrict__ Wp,
    const float* __restrict__ Wwp, const float* __restrict__ biasp,
    ushort_t* __restrict__ Ebf, ushort_t* __restrict__ Wpct,
    float* __restrict__ biasn, float* __restrict__ r) {
  const int gid = blockIdx.x * 256 + threadIdx.x;
  if (gid < NN) {
    r[gid] = 0.0f;  // zero rowsum accumulator (pgemm runs after prep)
    const float* e = E + (size_t)gid * EMB;
    ushort_t* o = Ebf + (size_t)gid * 32;
    #pragma unroll
    for (int d = 0; d < 16; ++d) o[d] = f2bf(e[d]);
    #pragma unroll
    for (int d = 16; d < 32; ++d) o[d] = 0;
  } else if (gid < 2 * NN) {
    const int j = gid - NN;
    const int oo = j >> 6;
    const int i = j & 63;
    const int q = i >> 4;
    const int ii = i & 15;
    ushort_t* w = Wpct + (size_t)j * 32;
    #pragma unroll
    for (int d = 0; d < 16; ++d) {
      float v;
      if (q == 0)
        v = Wp[((size_t)(d * 3 + 0) * 16 + ii) * 64 + oo] -
            Wp[((size_t)(d * 3 + 2) * 16 + ii) * 64 + oo];
      else if (q == 1)
        v = Wp[((size_t)(d * 3 + 1) * 16 + ii) * 64 + oo];
      else if (q == 2)
        v = 2.0f * Wp[((size_t)(d * 3 + 2) * 16 + ii) * 64 + oo];
      else
        v = Wwp[((size_t)d * 16 + ii) * 64 + oo];
      w[d] = f2bf(v);
    }
    #pragma unroll
    for (int d = 16; d < 32; ++d) w[d] = 0;
  } else {
    const int t = gid - 2 * NN;
    if (t < NN * 16) {
      const int n = t >> 4;
      const int o4 = t & 15;
      const float4* bp4 = reinterpret_cast<const float4*>(biasp);
      float4 acc = make_float4(0.f, 0.f, 0.f, 0.f);
      #pragma unroll
      for (int d = 0; d < 16; ++d) {
        const float e = E[(size_t)n * EMB + d];
        const float4 b = bp4[d * 16 + o4];
        acc.x += e * b.x; acc.y += e * b.y; acc.z += e * b.z; acc.w += e * b.w;
      }
      *reinterpret_cast<float4*>(biasn + (size_t)n * 64 + o4 * 4) = acc;
    }
  }
}

// ---------------------------------------------------------------------------
// Kernel 1: uber — heterogeneous fusion of {pgemm, Wall gemm, time_mix,
// transpose_x}: 7168 blocks = 512 groups x 14, interleaved 4:4:2:4 so each
// CU co-resides MFMA/L2-bound blocks with the HBM-latency-bound xw gather
// (R6-verified: time ~ max, tm rides over ~34 us of other work). R8 showed
// tm does NOT overlap with HBM-hungry splitk, so it lives here.
// ---------------------------------------------------------------------------
__global__ __launch_bounds__(256) void uber_kernel(
    const ushort_t* __restrict__ Ebf, const ushort_t* __restrict__ Wpct,
    ushort_t* __restrict__ Wall, ushort_t* __restrict__ Pb,
    float* __restrict__ r,
    const float* __restrict__ x, const float* __restrict__ xw,
    const float* __restrict__ Tv,
    ushort_t* __restrict__ XtT, float* __restrict__ XW) {
  __shared__ ushort_t smem[6144];  // 12 KB: GEMM As(4096)+Bs(2048) / tx tile
  const int bid = blockIdx.x;
  const int tid = threadIdx.x;
  const int g = bid / 14;
  const int rm = bid - g * 14;

  if (rm < 4) {
    // ---- pgemm: Pb = exp(relu(E E^T)-16) bf16 + rowsums (atomics) ----
    const int pidx = g * 4 + rm;          // 0..2047
    const int row0 = (pidx >> 6) * 128;
    const int col0 = (pidx & 63) * 64;
    ushort_t* As = smem;                  // 128x32
    ushort_t* Bs = smem + 4096;           // 64x32
    const int lane = tid & 63;
    const int wid = tid >> 6;
    const int wr = wid >> 1;
    const int wc = wid & 1;
    const int sr = tid >> 2;
    const int scs = (((tid & 3) ^ (sr & 3)) * 8);
    gload16(Ebf + (size_t)(row0 + sr) * 32 + scs, &As[tid * 8]);
    gload16(Ebf + (size_t)(row0 + 64 + sr) * 32 + scs, &As[2048 + tid * 8]);
    gload16(Ebf + (size_t)(col0 + sr) * 32 + scs, &Bs[tid * 8]);
    __syncthreads();

    const int kq = (lane >> 4) * 8;
    const int fr = lane & 15;
    bf16x8 af[4], bfr[2];
    #pragma unroll
    for (int i = 0; i < 4; ++i) {
      const int rr = wr * 64 + i * 16 + fr;
      af[i] = *reinterpret_cast<const bf16x8*>(&As[rr * 32 + (kq ^ ((rr & 3) * 8))]);
    }
    #pragma unroll
    for (int j = 0; j < 2; ++j) {
      const int rr = wc * 32 + j * 16 + fr;
      bfr[j] = *reinterpret_cast<const bf16x8*>(&Bs[rr * 32 + (kq ^ ((rr & 3) * 8))]);
    }
    f32x4 acc[4][2];
    #pragma unroll
    for (int i = 0; i < 4; ++i)
      #pragma unroll
      for (int j = 0; j < 2; ++j) acc[i][j] = (f32x4){0.f, 0.f, 0.f, 0.f};
    #pragma unroll
    for (int i = 0; i < 4; ++i)
      #pragma unroll
      for (int j = 0; j < 2; ++j)
        acc[i][j] = __builtin_amdgcn_mfma_f32_16x16x32_bf16(af[i], bfr[j],
                                                            acc[i][j], 0, 0, 0);
    float pv[4][2][4];
    #pragma unroll
    for (int i = 0; i < 4; ++i) {
      const int rg = row0 + wr * 64 + i * 16 + ((lane >> 4) << 2);
      #pragma unroll
      for (int j = 0; j < 2; ++j) {
        const int cg = col0 + wc * 32 + j * 16 + (lane & 15);
        us4 o;
        #pragma unroll
        for (int q = 0; q < 4; ++q) {
          const float p = __expf(fmaxf(acc[i][j][q], 0.0f) - 16.0f);
          pv[i][j][q] = p;
          o[q] = f2bf(p);
        }
        *reinterpret_cast<us4*>(&Pb[(size_t)cg * NN + rg]) = o;
      }
    }
    #pragma unroll
    for (int i = 0; i < 4; ++i) {
      const int rg = row0 + wr * 64 + i * 16 + ((lane >> 4) << 2);
      #pragma unroll
      for (int q = 0; q < 4; ++q) {
        float s = pv[i][0][q] + pv[i][1][q];
        s += __shfl_xor(s, 1, 64);
        s += __shfl_xor(s, 2, 64);
        s += __shfl_xor(s, 4, 64);
        s += __shfl_xor(s, 8, 64);
        if ((lane & 15) == 0) atomicAdd(&r[rg + q], s);
      }
    }
  } else if (rm < 8) {
    // ---- Wall gemm: Wall[n][j'] = (Wpct @ Ebf^T)^T, K=32 single-step ----
    const int widx = g * 4 + (rm - 4);    // 0..2047
    const int row0 = (widx >> 6) * 128;   // j' rows
    const int col0 = (widx & 63) * 64;    // n cols
    ushort_t* As = smem;
    ushort_t* Bs = smem + 4096;
    const int lane = tid & 63;
    const int wid = tid >> 6;
    const int wr = wid >> 1;
    const int wc = wid & 1;
    const int sr = tid >> 2;
    const int scs = (((tid & 3) ^ (sr & 3)) * 8);
    gload16(Wpct + (size_t)(row0 + sr) * 32 + scs, &As[tid * 8]);
    gload16(Wpct + (size_t)(row0 + 64 + sr) * 32 + scs, &As[2048 + tid * 8]);
    gload16(Ebf + (size_t)(col0 + sr) * 32 + scs, &Bs[tid * 8]);
    __syncthreads();

    const int kq = (lane >> 4) * 8;
    const int fr = lane & 15;
    bf16x8 af[4], bfr[2];
    #pragma unroll
    for (int i = 0; i < 4; ++i) {
      const int rr = wr * 64 + i * 16 + fr;
      af[i] = *reinterpret_cast<const bf16x8*>(&As[rr * 32 + (kq ^ ((rr & 3) * 8))]);
    }
    #pragma unroll
    for (int j = 0; j < 2; ++j) {
      const int rr = wc * 32 + j * 16 + fr;
      bfr[j] = *reinterpret_cast<const bf16x8*>(&Bs[rr * 32 + (kq ^ ((rr & 3) * 8))]);
    }
    f32x4 acc[4][2];
    #pragma unroll
    for (int i = 0; i < 4; ++i)
      #pragma unroll
      for (int j = 0; j < 2; ++j) acc[i][j] = (f32x4){0.f, 0.f, 0.f, 0.f};
    #pragma unroll
    for (int i = 0; i < 4; ++i)
      #pragma unroll
      for (int j = 0; j < 2; ++j)
        acc[i][j] = __builtin_amdgcn_mfma_f32_16x16x32_bf16(af[i], bfr[j],
                                                            acc[i][j], 0, 0, 0);
    #pragma unroll
    for (int i = 0; i < 4; ++i) {
      const int rg = row0 + wr * 64 + i * 16 + ((lane >> 4) << 2);
      #pragma unroll
      for (int j = 0; j < 2; ++j) {
        const int cg = col0 + wc * 32 + j * 16 + (lane & 15);
        us4 o;
        o.x = f2bf(acc[i][j][0]);
        o.y = f2bf(acc[i][j][1]);
        o.z = f2bf(acc[i][j][2]);
        o.w = f2bf(acc[i][j][3]);
        *reinterpret_cast<us4*>(&Wall[(size_t)cg * NN + rg]) = o;
      }
    }
  } else if (rm < 10) {
    // ---- time_mix: XW[b][n][i] = sum_t xw[b][t][n][i]*T[t] ----
    const int tidx = g * 2 + (rm - 8);    // 0..1023
    const int lin = tidx * 256 + tid;
    const int c4 = (lin & 3) << 2;
    const int nn0 = ((lin >> 6) & 127) * 32 + ((lin >> 2) & 15);
    const int b = lin >> 13;
    float tv[WWIN];
    #pragma unroll
    for (int t = 0; t < WWIN; ++t) tv[t] = Tv[t];
    float4 a0 = make_float4(0.f, 0.f, 0.f, 0.f);
    float4 a1 = make_float4(0.f, 0.f, 0.f, 0.f);
    #pragma unroll 3
    for (int t = 0; t < WWIN; ++t) {
      const float4 v0 = nt_load4(
          xw + (((size_t)b * WWIN + t) * NN + nn0) * CIN + c4);
      const float4 v1 = nt_load4(
          xw + (((size_t)b * WWIN + t) * NN + nn0 + 16) * CIN + c4);
      a0.x += v0.x * tv[t]; a0.y += v0.y * tv[t];
      a0.z += v0.z * tv[t]; a0.w += v0.w * tv[t];
      a1.x += v1.x * tv[t]; a1.y += v1.y * tv[t];
      a1.z += v1.z * tv[t]; a1.w += v1.w * tv[t];
    }
    *reinterpret_cast<float4*>(XW + ((size_t)b * NN + nn0) * CIN + c4) = a0;
    *reinterpret_cast<float4*>(XW + ((size_t)b * NN + nn0 + 16) * CIN + c4) = a1;
  } else {
    // ---- transpose_x: XtT[b*CIN+c][m] = bf16(x[b][m][c]) ----
    const int txidx = g * 4 + (rm - 10);  // 0..2047
    const int b = txidx >> 6;
    const int m0 = (txidx & 63) * 64;
    ushort_t (*T)[72] = reinterpret_cast<ushort_t(*)[72]>(smem);
    const int i = tid & 15;
    const int ml = tid >> 4;
    #pragma unroll
    for (int it = 0; it < 4; ++it) {
      const int m = m0 + ml + it * 16;
      T[i][ml + it * 16] = f2bf(x[((size_t)b * NN + m) * CIN + i]);
    }
    __syncthreads();
    if (tid < 128) {
      const int rr = tid >> 3;
      const int c8 = (tid & 7) * 8;
      const us8 v = *reinterpret_cast<const us8*>(&T[rr][c8]);
      *reinterpret_cast<us8*>(&XtT[(size_t)(b * CIN + rr) * NN + m0 + c8]) = v;
    }
  }
}

// ---------------------------------------------------------------------------
// Kernel 2b: split-K MFMA GEMM — depth-2 software pipeline (T3/T4).
// 3 LDS buffers (36 KB -> 4 blocks/CU); loads for tile t are issued at
// iteration t-2; raw s_barrier + counted s_waitcnt vmcnt(6) keeps 2 tiles
// of loads in flight ACROSS barriers. vmcnt N = 3 loads/tile x 2 tiles.
// Main loop statically unrolled x3 so buffer indices are compile-time.
// XCD chunk-swizzle (bijective, nwg%8==0) for A-panel L2 locality.
// ---------------------------------------------------------------------------
template <int CUR>
__device__ __forceinline__ void compute_tile(
    const ushort_t (&As)[3][128 * 32], const ushort_t (&Bs)[3][64 * 32],
    f32x4 (&acc)[4][2], int wr, int wc, int kq, int fr) {
  bf16x8 af[4], bfr[2];
  #pragma unroll
  for (int i = 0; i < 4; ++i) {
    const int rr = wr * 64 + i * 16 + fr;
    af[i] = *reinterpret_cast<const bf16x8*>(
        &As[CUR][rr * 32 + (kq ^ ((rr & 3) * 8))]);
  }
  #pragma unroll
  for (int j = 0; j < 2; ++j) {
    const int rr = wc * 32 + j * 16 + fr;
    bfr[j] = *reinterpret_cast<const bf16x8*>(
        &Bs[CUR][rr * 32 + (kq ^ ((rr & 3) * 8))]);
  }
  #pragma unroll
  for (int i = 0; i < 4; ++i)
    #pragma unroll
    for (int j = 0; j < 2; ++j)
      acc[i][j] = __builtin_amdgcn_mfma_f32_16x16x32_bf16(af[i], bfr[j],
                                                          acc[i][j], 0, 0, 0);
}

__global__ __launch_bounds__(256) void gemm_splitk_kernel(
    const ushort_t* __restrict__ Ag, const ushort_t* __restrict__ Bt,
    float* __restrict__ Cp, int lda, int ldb, int ldc) {
  __shared__ ushort_t As[3][128 * 32];
  __shared__ ushort_t Bs[3][64 * 32];
  const int tid = threadIdx.x;
  const int lane = tid & 63;
  const int wid = tid >> 6;
  const int wr = wid >> 1;
  const int wc = wid & 1;

  // XCD-aware bijective remap of the full linear block id.
  const int gx = gridDim.x, gy = gridDim.y;
  const int nwg = gx * gy * gridDim.z;   // 1024 (divisible by 8)
  int L = blockIdx.x + gx * (blockIdx.y + gy * blockIdx.z);
  L = (L & 7) * (nwg >> 3) + (L >> 3);
  const int bx = L % gx;
  const int by = (L / gx) % gy;
  const int bz = L / (gx * gy);

  const int row0 = by * 128;
  const int col0 = bx * 64;
  const int kbase = bz * KCHUNK;

  f32x4 acc[4][2];
  #pragma unroll
  for (int i = 0; i < 4; ++i)
    #pragma unroll
    for (int j = 0; j < 2; ++j) acc[i][j] = (f32x4){0.f, 0.f, 0.f, 0.f};

  const int sr = tid >> 2;
  const int scs = (((tid & 3) ^ (sr & 3)) * 8);
  const ushort_t* agp0 = Ag + (size_t)(row0 + sr) * lda + scs;
  const ushort_t* agp1 = Ag + (size_t)(row0 + 64 + sr) * lda + scs;
  const ushort_t* bgp  = Bt + (size_t)(col0 + sr) * ldb + scs;

  const int kq = (lane >> 4) * 8;
  const int fr = lane & 15;

#define STAGE(BUF, KB)                              \
  gload16(agp0 + (KB), &As[BUF][tid * 8]);          \
  gload16(agp1 + (KB), &As[BUF][2048 + tid * 8]);   \
  gload16(bgp + (KB), &Bs[BUF][tid * 8]);

#define PIPE_STEP(CUR, NB, TT)                                  \
  STAGE(NB, kbase + ((TT) + 2) * 32);                           \
  asm volatile("s_waitcnt vmcnt(6)" ::: "memory");              \
  __builtin_amdgcn_s_barrier();                                 \
  __builtin_amdgcn_sched_barrier(0);                            \
  compute_tile<CUR>(As, Bs, acc, wr, wc, kq, fr);               \
  __builtin_amdgcn_sched_barrier(0);                            \
  __builtin_amdgcn_s_barrier();

  // prologue: stage tiles 0 and 1 (6 loads in flight per thread)
  STAGE(0, kbase);
  STAGE(1, kbase + 32);

  // main loop: t = 0..NT-3, statically unrolled x3 (NT-2 = 30 = 3*10)
  for (int tt = 0; tt < (NT - 2) / 3; ++tt) {
    const int t3 = tt * 3;
    PIPE_STEP(0, 2, t3 + 0);
    PIPE_STEP(1, 0, t3 + 1);
    PIPE_STEP(2, 1, t3 + 2);
  }
  // tail t = NT-2 (cur = 0): only tile NT-1's 3 loads outstanding
  asm volatile("s_waitcnt vmcnt(3)" ::: "memory");
  __builtin_amdgcn_s_barrier();
  __builtin_amdgcn_sched_barrier(0);
  compute_tile<0>(As, Bs, acc, wr, wc, kq, fr);
  __builtin_amdgcn_sched_barrier(0);
  __builtin_amdgcn_s_barrier();
  // tail t = NT-1 (cur = 1)
  asm volatile("s_waitcnt vmcnt(0)" ::: "memory");
  __builtin_amdgcn_s_barrier();
  __builtin_amdgcn_sched_barrier(0);
  compute_tile<1>(As, Bs, acc, wr, wc, kq, fr);

#undef PIPE_STEP
#undef STAGE

  float* cpz = Cp + (size_t)bz * ((size_t)BCIN * NN);
  #pragma unroll
  for (int i = 0; i < 4; ++i) {
    const int rg = row0 + wr * 64 + i * 16 + ((lane >> 4) << 2);
    #pragma unroll
    for (int j = 0; j < 2; ++j) {
      const int cg = col0 + wc * 32 + j * 16 + (lane & 15);
      *reinterpret_cast<f32x4*>(&cpz[(size_t)cg * ldc + rg]) = acc[i][j];
    }
  }
}

// ---------------------------------------------------------------------------
// Kernel 2c: Y1 reduce + transpose (fused). Sums KSPLIT f32 partials of
// Cpart[bc][n], scales by 1/R[n], writes Y1T[bc][n] (coalesced) AND
// Y1n[n][bc] via LDS 64x64 transpose. grid (NN/64, BCIN/64) = 512 blocks.
// ---------------------------------------------------------------------------
__global__ __launch_bounds__(256) void reduce_y1_kernel(
    const float* __restrict__ Cp, const float* __restrict__ R,
    ushort_t* __restrict__ Y1T, ushort_t* __restrict__ Y1n) {
  __shared__ ushort_t T[64][72];
  const int n0 = blockIdx.x * 64;
  const int bc0 = blockIdx.y * 64;
  const int tid = threadIdx.x;
  const size_t SS = (size_t)BCIN * NN;
  #pragma unroll
  for (int q = 0; q < 4; ++q) {
    const int lin = tid + q * 256;
    const int bc = lin >> 4;          // 0..63
    const int nc = (lin & 15) * 4;    // 0..60
    const size_t base = (size_t)(bc0 + bc) * NN + n0 + nc;
    float4 s = *reinterpret_cast<const float4*>(Cp + base);
    #pragma unroll
    for (int z = 1; z < KSPLIT; ++z) {
      const float4 v = *reinterpret_cast<const float4*>(Cp + (size_t)z * SS + base);
      s.x += v.x; s.y += v.y; s.z += v.z; s.w += v.w;
    }
    const float4 rv = *reinterpret_cast<const float4*>(R + n0 + nc);
    us4 o;
    o.x = f2bf(s.x / rv.x); o.y = f2bf(s.y / rv.y);
    o.z = f2bf(s.z / rv.z); o.w = f2bf(s.w / rv.w);
    *reinterpret_cast<us4*>(&Y1T[base]) = o;
    *reinterpret_cast<us4*>(&T[bc][nc]) = o;
  }
  __syncthreads();
  #pragma unroll
  for (int t = 0; t < 2; ++t) {
    const int lin = tid + t * 256;
    const int nr = lin >> 3;
    const int ch = lin & 7;
    us8 v;
    #pragma unroll
    for (int e = 0; e < 8; ++e) v[e] = T[ch * 8 + e][nr];
    *reinterpret_cast<us8*>(&Y1n[(size_t)(n0 + nr) * BCIN + bc0 + ch * 8]) = v;
  }
}

// ---------------------------------------------------------------------------
// Kernel 7: combine via per-node MFMA, with reduce_y2 FOLDED IN. One wave
// per node (2 nodes/wave), 512 blocks x 4 waves. Per node:
//   out[32b x 64o] = V[32x64] @ W[64x64] + bias
// The Y2 quarter of V is computed inline from the splitk2 f32 partials:
//   y2 = f2bf((sum_z Cpart[z][n*BCIN+bc]) / R[n])   (z ascending -> exact
// same FP order + ops as the old reduce_y2 kernel -> identical bits).
// ---------------------------------------------------------------------------
__global__ __launch_bounds__(256) void combine_kernel(
    const float* __restrict__ x, const ushort_t* __restrict__ Y1n,
    const float* __restrict__ Cp2, const float* __restrict__ R,
    const float* __restrict__ XW,
    const ushort_t* __restrict__ Wall, const float* __restrict__ biasn,
    float* __restrict__ out) {
  __shared__ ushort_t lds[4 * 6144];  // per wave: W 4096 us + V 2048 us
  const int tid = threadIdx.x;
  const int lane = tid & 63;
  const int w = tid >> 6;
  ushort_t* Wl = lds + w * 6144;
  ushort_t* Vl = Wl + 4096;
  const size_t SS = (size_t)BCIN * NN;

  const int perm = ((lane >> 3) << 3) | ((lane & 7) ^ (lane >> 3));
  const int vb = lane >> 1;
  const int i0 = (lane & 1) * 8;

  for (int it = 0; it < 2; ++it) {
    const int n = blockIdx.x * 8 + w * 2 + it;
    asm volatile("s_waitcnt lgkmcnt(0)" ::: "memory");

    const ushort_t* wrow = Wall + (size_t)n * 4096;
    #pragma unroll
    for (int q = 0; q < 8; ++q)
      gload16(wrow + q * 512 + perm * 8, Wl + q * 512);

    const float4* xp = reinterpret_cast<const float4*>(
        x + ((size_t)vb * NN + n) * CIN + i0);
    const float4 xa = xp[0], xb = xp[1];
    const us8 y1 = *reinterpret_cast<const us8*>(Y1n + (size_t)n * BCIN + lane * 8);

    // inline reduce_y2: sum 4 f32 partials, scale by 1/R[n], to bf16
    const float* cp2 = Cp2 + (size_t)n * BCIN + lane * 8;
    float4 s0 = *reinterpret_cast<const float4*>(cp2);
    float4 s1 = *reinterpret_cast<const float4*>(cp2 + 4);
    #pragma unroll
    for (int z = 1; z < KSPLIT; ++z) {
      const float4 v0 = *reinterpret_cast<const float4*>(cp2 + (size_t)z * SS);
      const float4 v1 = *reinterpret_cast<const float4*>(cp2 + (size_t)z * SS + 4);
      s0.x += v0.x; s0.y += v0.y; s0.z += v0.z; s0.w += v0.w;
      s1.x += v1.x; s1.y += v1.y; s1.z += v1.z; s1.w += v1.w;
    }
    const float ri = 1.0f / R[n];
    us8 y2;
    y2[0] = f2bf(s0.x * ri); y2[1] = f2bf(s0.y * ri);
    y2[2] = f2bf(s0.z * ri); y2[3] = f2bf(s0.w * ri);
    y2[4] = f2bf(s1.x * ri); y2[5] = f2bf(s1.y * ri);
    y2[6] = f2bf(s1.z * ri); y2[7] = f2bf(s1.w * ri);

    const float4* xwp = reinterpret_cast<const float4*>(
        XW + ((size_t)vb * NN + n) * CIN + i0);
    const float4 wa = xwp[0], wb = xwp[1];
    us8 xv, wv;
    xv[0] = f2bf(xa.x); xv[1] = f2bf(xa.y); xv[2] = f2bf(xa.z); xv[3] = f2bf(xa.w);
    xv[4] = f2bf(xb.x); xv[5] = f2bf(xb.y); xv[6] = f2bf(xb.z); xv[7] = f2bf(xb.w);
    wv[0] = f2bf(wa.x); wv[1] = f2bf(wa.y); wv[2] = f2bf(wa.z); wv[3] = f2bf(wa.w);
    wv[4] = f2bf(wb.x); wv[5] = f2bf(wb.y); wv[6] = f2bf(wb.z); wv[7] = f2bf(wb.w);
    const int c0 = (lane & 1);
    const int vswz = vb & 7;
    *reinterpret_cast<us8*>(Vl + vb * 64 + (((c0 + 0) ^ vswz) << 3)) = xv;
    *reinterpret_cast<us8*>(Vl + vb * 64 + (((c0 + 2) ^ vswz) << 3)) = y1;
    *reinterpret_cast<us8*>(Vl + vb * 64 + (((c0 + 4) ^ vswz) << 3)) = y2;
    *reinterpret_cast<us8*>(Vl + vb * 64 + (((c0 + 6) ^ vswz) << 3)) = wv;

    f32x4 acc[2][4];
    #pragma unroll
    for (int nt = 0; nt < 4; ++nt) {
      const float bv = biasn[(size_t)n * 64 + nt * 16 + (lane & 15)];
      acc[0][nt] = (f32x4){bv, bv, bv, bv};
      acc[1][nt] = (f32x4){bv, bv, bv, bv};
    }

    asm volatile("s_waitcnt vmcnt(0)" ::: "memory");

    bf16x8 af[2][2], bfr[4][2];
    #pragma unroll
    for (int mt = 0; mt < 2; ++mt)
      #pragma unroll
      for (int kt = 0; kt < 2; ++kt) {
        const int rr = mt * 16 + (lane & 15);
        const int c = kt * 4 + (lane >> 4);
        af[mt][kt] = *reinterpret_cast<const bf16x8*>(
            Vl + rr * 64 + ((c ^ (lane & 7)) << 3));
      }
    #pragma unroll
    for (int nt = 0; nt < 4; ++nt)
      #pragma unroll
      for (int kt = 0; kt < 2; ++kt) {
        const int o = nt * 16 + (lane & 15);
        const int c = kt * 4 + (lane >> 4);
        bfr[nt][kt] = *reinterpret_cast<const bf16x8*>(
            Wl + o * 64 + ((c ^ (lane & 7)) << 3));
      }
    #pragma unroll
    for (int mt = 0; mt < 2; ++mt)
      #pragma unroll
      for (int nt = 0; nt < 4; ++nt)
        #pragma unroll
        for (int kt = 0; kt < 2; ++kt)
          acc[mt][nt] = __builtin_amdgcn_mfma_f32_16x16x32_bf16(
              af[mt][kt], bfr[nt][kt], acc[mt][nt], 0, 0, 0);

    #pragma unroll
    for (int mt = 0; mt < 2; ++mt)
      #pragma unroll
      for (int nt = 0; nt < 4; ++nt) {
        const int o = nt * 16 + (lane & 15);
        #pragma unroll
        for (int rr = 0; rr < 4; ++rr) {
          const int b = mt * 16 + ((lane >> 4) << 2) + rr;
          out[((size_t)b * NN + n) * COUT + o] = acc[mt][nt][rr];
        }
      }
  }
}

// ---------------------------------------------------------------------------
extern "C" void kernel_launch(void* const* d_in, const int* in_sizes, int n_in,
                              void* d_out, int out_size, void* d_ws,
                              size_t ws_size, hipStream_t stream) {
  const float* x = (const float*)d_in[0];        // [B,N,CIN]
  const float* x_window = (const float*)d_in[1]; // [B,WIN,N,CIN]
  const float* E = (const float*)d_in[2];        // [N,EMB]
  const float* Wp = (const float*)d_in[3];       // [EMB,K,CIN,COUT]
  const float* Wwp = (const float*)d_in[4];      // [EMB,CIN,COUT]
  const float* biasp = (const float*)d_in[5];    // [EMB,COUT]
  const float* Tv = (const float*)d_in[6];       // [WIN]
  float* out = (float*)d_out;                    // [B,N,COUT] f32

  // Workspace layout
  char* p = (char*)d_ws;
  float* XW = (float*)p;                 p += (size_t)BB * NN * CIN * 4;
  ushort_t* Pb = (ushort_t*)p;           p += (size_t)NN * NN * 2;
  ushort_t* XtT = (ushort_t*)p;          p += (size_t)BCIN * NN * 2;
  ushort_t* Y1T = (ushort_t*)p;          p += (size_t)BCIN * NN * 2;
  ushort_t* Y1n = (ushort_t*)p;          p += (size_t)NN * BCIN * 2;
  ushort_t* Wall = (ushort_t*)p;         p += (size_t)NN * 4096 * 2;
  ushort_t* Ebf = (ushort_t*)p;          p += (size_t)NN * 32 * 2;
  ushort_t* Wpct = (ushort_t*)p;         p += (size_t)NN * 32 * 2;
  float* biasn = (float*)p;              p += (size_t)NN * 64 * 4;
  float* r = (float*)p;                  p += (size_t)NN * 4;
  float* Cpart = (float*)p;              p += (size_t)KSPLIT * BCIN * NN * 4;

  // prep (tiny) -> uber {pgemm + Wall + time_mix + transpose_x} fused
  // (R6-best structure: tm overlaps with compute/L2-bound blocks only).
  prep_kernel<<<288, 256, 0, stream>>>(E, Wp, Wwp, biasp, Ebf, Wpct, biasn, r);
  uber_kernel<<<7168, 256, 0, stream>>>(Ebf, Wpct, Wall, Pb, r,
                                        x, x_window, Tv, XtT, XW);
  // Y1 partials: (P Xt)^T layout [bc][n], f32, via depth-2 pipelined split-K
  gemm_splitk_kernel<<<dim3(BCIN / 64, NN / 128, KSPLIT), 256, 0, stream>>>(
      Pb, XtT, Cpart, NN, NN, NN);
  // Y1 reduce + normalize + dual-layout store (Y1T + Y1n)
  reduce_y1_kernel<<<dim3(NN / 64, BCIN / 64), 256, 0, stream>>>(
      Cpart, r, Y1T, Y1n);
  // Y2 partials: layout [n][bc] (consumed raw by combine's inline reduce)
  gemm_splitk_kernel<<<dim3(NN / 64, BCIN / 128, KSPLIT), 256, 0, stream>>>(
      Y1T, Pb, Cpart, NN, NN, BCIN);
  // combine: per-node V[32x64] @ W[64x64] + bias, with inline Y2 reduce
  combine_kernel<<<NN / 8, 256, 0, stream>>>(x, Y1n, Cpart, r, XW,
                                             Wall, biasn, out);
}